// Round 11
// baseline (199.510 us; speedup 1.0000x reference)
//
#include <hip/hip_runtime.h>
#include <hip/hip_cooperative_groups.h>
#include <float.h>
#include <stdint.h>

namespace cg = cooperative_groups;

// WindowRouting: out[b][q][0..3] = indices of top-4 of (Q[b,q,:] . I[b,m,:]) over m.
// Scale dropped (order-preserving).
//
// R10 LESSON: each extra dispatch costs ~25-30 us fixed (total - sum(kernels)
// is ~25 us/dispatch across R1..R10); occupancy tweaks don't pay. So: ONE
// cooperative kernel (256 blocks x 512 thr = 1 block/CU, co-resident by
// construction):
//   Phase 1: distributed fp32->bf16 convert (query linear; image LDS-transposed
//     to 16x16x32-fragment-linear tiles — identical math to the proven cvt).
//   __threadfence + grid.sync()
//   Phase 2: R8's proven MFMA screen + fp64 refine body, verbatim.
// Host fallback: if hipLaunchCooperativeKernel errors, run the proven R8
// two-kernel path. Tier-3: fp32 LDS fallback for tiny ws.

#define NBATCH 4
#define NQ 4096
#define NM 8192
#define KD 128

typedef unsigned short ushort_t;
typedef __attribute__((ext_vector_type(8))) short bf16x8;
typedef __attribute__((ext_vector_type(4))) float f32x4;

#define BETTER64(v, i, w, j) (((v) > (w)) || ((v) == (w) && (i) < (j)))

__device__ inline float fmed3(float a, float b, float c) {
#if __has_builtin(__builtin_amdgcn_fmed3f)
  return __builtin_amdgcn_fmed3f(a, b, c);
#else
  return fmaxf(fminf(a, b), fminf(fmaxf(a, b), c));
#endif
}

__device__ inline ushort_t f2bf(float f) {
  unsigned u = __float_as_uint(f);
  u += 0x7fffu + ((u >> 16) & 1u);  // RNE
  return (ushort_t)(u >> 16);
}

// ---------------- Fused cooperative kernel ----------------
__global__ __launch_bounds__(512, 1) void wr_fused(const float* __restrict__ qry,
                                                   const float* __restrict__ img,
                                                   ushort_t* __restrict__ qb,
                                                   int4* __restrict__ ib,
                                                   int* __restrict__ out) {
  const int tid = (int)threadIdx.x;
  const int bid = (int)blockIdx.x;  // 0..255

  __shared__ __align__(16) ushort_t T[2][32 * 128];  // phase-1 transpose buffers

  // ======== Phase 1a: query convert (4 float4 chunks per thread) ========
  {
    const int g = bid * 512 + tid;  // 0..131071
#pragma unroll
    for (int i = 0; i < 4; ++i) {
      const int t = g + i * 131072;  // covers 524288 chunks
      const float4 v = ((const float4*)qry)[t];
      ushort4 o;
      o.x = f2bf(v.x); o.y = f2bf(v.y); o.z = f2bf(v.z); o.w = f2bf(v.w);
      ((ushort4*)qb)[t] = o;
    }
  }

  // ======== Phase 1b: image convert+swizzle (4 tiles per block, 2 at a time) ==
  {
    const int sub = tid >> 8;   // 0..1 : which tile of the pair
    const int t2 = tid & 255;
    for (int it = 0; it < 2; ++it) {
      const int tg = bid * 4 + it * 2 + sub;  // 0..1023
      const int b = tg >> 8;
      const int tile = tg & 255;
      {
        const int r = t2 >> 3;
        const int seg = t2 & 7;
        const float* src = img + ((size_t)(b * NM + tile * 32 + r)) * KD + seg * 16;
        ushort_t tmp[16];
#pragma unroll
        for (int i = 0; i < 4; ++i) {
          const float4 v = ((const float4*)src)[i];
          tmp[i * 4 + 0] = f2bf(v.x);
          tmp[i * 4 + 1] = f2bf(v.y);
          tmp[i * 4 + 2] = f2bf(v.z);
          tmp[i * 4 + 3] = f2bf(v.w);
        }
        const int c0 = (seg * 16 + r * 8) & 127;
        const int c1 = (seg * 16 + 8 + r * 8) & 127;
        *(int4*)&T[sub][r * 128 + c0] = *(const int4*)&tmp[0];
        *(int4*)&T[sub][r * 128 + c1] = *(const int4*)&tmp[8];
      }
      __syncthreads();
      {
        int4* dstt = ib + ((size_t)b * 256 + tile) * 512;
#pragma unroll
        for (int h = 0; h < 2; ++h) {
          const int n = t2 + h * 256;
          const int l = n & 63;
          const int ks = (n >> 6) & 3;
          const int htl = n >> 8;
          const int row = htl * 16 + (l & 15);
          const int col = ks * 32 + (l >> 4) * 8;
          dstt[n] = *(const int4*)&T[sub][row * 128 + ((col + row * 8) & 127)];
        }
      }
      __syncthreads();  // T reused next iteration
    }
  }

  __threadfence();
  cg::this_grid().sync();

  // ======== Phase 2: R8's proven MFMA screen + fp64 refine ========
  const int b = (bid & 7) >> 1;                  // batch pinned to XCD pair
  const int qt = ((bid >> 3) << 1) | (bid & 1);  // 0..63
  const int qbase = qt * 64;

  const int lane = tid & 63;
  const int w = tid >> 6;      // 0..7 -> m-eighth (64 half-tiles of 16 m)
  const int q15 = lane & 15;
  const int quad = lane >> 4;  // 0..3

  const ushort_t* Qb = qb + ((size_t)b * NQ + qbase) * KD;
  const int4* ibc = ib + (size_t)b * 131072;

  bf16x8 bfrag[4][4];  // 4 strips of 16 q, pinned
#pragma unroll
  for (int s = 0; s < 4; ++s)
#pragma unroll
    for (int ks = 0; ks < 4; ++ks)
      bfrag[s][ks] =
          *(const bf16x8*)(Qb + (size_t)(s * 16 + q15) * KD + ks * 32 + quad * 8);

  float tch[4][4];
#pragma unroll
  for (int s = 0; s < 4; ++s)
#pragma unroll
    for (int e = 0; e < 4; ++e) tch[s][e] = -FLT_MAX;

  bf16x8 B0[4], B1[4], B2[4];

  auto loadH = [&](bf16x8* R, int h) {
    const int4* p = ibc + (((w * 64 + h) << 8) + lane);
#pragma unroll
    for (int ks = 0; ks < 4; ++ks) R[ks] = *(const bf16x8*)(p + ks * 64);
  };

  int hl = 3;
  int vb = 2047 - 4 * quad;  // m_local = 16*h + 4*quad + r (< 1024)

  auto step = [&](bf16x8* R) {
    f32x4 a[4];
#pragma unroll
    for (int s = 0; s < 4; ++s) a[s] = {0.f, 0.f, 0.f, 0.f};
#pragma unroll
    for (int ks = 0; ks < 4; ++ks)
#pragma unroll
      for (int s = 0; s < 4; ++s)
        a[s] = __builtin_amdgcn_mfma_f32_16x16x32_bf16(R[ks], bfrag[s][ks], a[s],
                                                       0, 0, 0);
    if (hl < 64) loadH(R, hl);
    ++hl;
#pragma unroll
    for (int s = 0; s < 4; ++s) {
#pragma unroll
      for (int r = 0; r < 4; ++r) {
        const unsigned kr = (unsigned)(vb - r);
        const float k =
            __uint_as_float((__float_as_uint(a[s][r]) & 0xFFFFF800u) | kr);
        tch[s][3] = fmed3(k, tch[s][2], tch[s][3]);
        tch[s][2] = fmed3(k, tch[s][1], tch[s][2]);
        tch[s][1] = fmed3(k, tch[s][0], tch[s][1]);
        tch[s][0] = fmaxf(tch[s][0], k);
      }
    }
    vb -= 16;
  };

  loadH(B0, 0);
  loadH(B1, 1);
  loadH(B2, 2);
  for (int g = 0; g < 21; ++g) { step(B0); step(B1); step(B2); }
  step(B0);  // half-tile 63

  // quad-tree merge (snapshot donor regs BEFORE mutating — R4 lesson)
#pragma unroll
  for (int s = 0; s < 4; ++s) {
    float k4[4];
#pragma unroll
    for (int e = 0; e < 4; ++e) k4[e] = __shfl_down(tch[s][e], 32, 64);
#pragma unroll
    for (int e = 0; e < 4; ++e) {
      const float k = k4[e];
      tch[s][3] = fmed3(k, tch[s][2], tch[s][3]);
      tch[s][2] = fmed3(k, tch[s][1], tch[s][2]);
      tch[s][1] = fmed3(k, tch[s][0], tch[s][1]);
      tch[s][0] = fmaxf(tch[s][0], k);
    }
#pragma unroll
    for (int e = 0; e < 4; ++e) k4[e] = __shfl_down(tch[s][e], 16, 64);
#pragma unroll
    for (int e = 0; e < 4; ++e) {
      const float k = k4[e];
      tch[s][3] = fmed3(k, tch[s][2], tch[s][3]);
      tch[s][2] = fmed3(k, tch[s][1], tch[s][2]);
      tch[s][1] = fmed3(k, tch[s][0], tch[s][1]);
      tch[s][0] = fmaxf(tch[s][0], k);
    }
  }

  __shared__ float ck[64][33];
  __shared__ int top8[64][8];
  __shared__ double pd[64][8];
  __shared__ int pi[64][8];

  if (lane < 16) {
#pragma unroll
    for (int s = 0; s < 4; ++s)
#pragma unroll
      for (int e = 0; e < 4; ++e) ck[s * 16 + q15][w * 4 + e] = tch[s][e];
  }
  __syncthreads();

  for (int p = tid; p < 2048; p += 512) {
    const int q = p >> 5;
    const int j = p & 31;
    const float k = ck[q][j];
    int rank = 0;
#pragma unroll 8
    for (int i = 0; i < 32; ++i) {
      const float o = ck[q][i];
      rank += (o > k) || (o == k && i < j);
    }
    if (rank < 8) {
      const unsigned bits = __float_as_uint(k);
      top8[q][rank] = (j >> 2) * 1024 + 2047 - (int)(bits & 0x7FFu);
    }
  }
  __syncthreads();

  {
    const int q = tid >> 3;
    const int slot = tid & 7;
    const int m = top8[q][slot];
    const float* qrow = qry + ((size_t)b * NQ + qbase + q) * KD;
    const float* irow = img + ((size_t)b * NM + m) * KD;
    double s0 = 0.0, s1 = 0.0, s2 = 0.0, s3 = 0.0;
#pragma unroll
    for (int k = 0; k < KD; k += 4) {
      const float4 xv = *(const float4*)(qrow + k);
      const float4 yv = *(const float4*)(irow + k);
      s0 = fma((double)xv.x, (double)yv.x, s0);
      s1 = fma((double)xv.y, (double)yv.y, s1);
      s2 = fma((double)xv.z, (double)yv.z, s2);
      s3 = fma((double)xv.w, (double)yv.w, s3);
    }
    pd[q][slot] = (s0 + s1) + (s2 + s3);
    pi[q][slot] = m;
  }
  __syncthreads();

  if (tid < 64) {
    const int q = tid;
    double fv[4];
    int fi[4];
#pragma unroll
    for (int e = 0; e < 4; ++e) { fv[e] = -DBL_MAX; fi[e] = 0x7fffffff; }
    for (int sl = 0; sl < 8; ++sl) {
      const double v = pd[q][sl];
      const int m = pi[q][sl];
      const bool b0 = BETTER64(v, m, fv[0], fi[0]);
      const bool b1 = BETTER64(v, m, fv[1], fi[1]);
      const bool b2 = BETTER64(v, m, fv[2], fi[2]);
      const bool b3 = BETTER64(v, m, fv[3], fi[3]);
      fv[3] = b2 ? fv[2] : (b3 ? v : fv[3]);
      fi[3] = b2 ? fi[2] : (b3 ? m : fi[3]);
      fv[2] = b1 ? fv[1] : (b2 ? v : fv[2]);
      fi[2] = b1 ? fi[1] : (b2 ? m : fi[2]);
      fv[1] = b0 ? fv[0] : (b1 ? v : fv[1]);
      fi[1] = b0 ? fi[0] : (b1 ? m : fi[1]);
      fv[0] = b0 ? v : fv[0];
      fi[0] = b0 ? m : fi[0];
    }
    int4 o;
    o.x = fi[0]; o.y = fi[1]; o.z = fi[2]; o.w = fi[3];
    *(int4*)(out + ((size_t)b * NQ + qbase + q) * 4) = o;
  }
}

// ---------------- Fallback K0: convert + swizzle (proven R7/R8) ----------------
__global__ __launch_bounds__(256) void wr_cvt(const float* __restrict__ qry,
                                              const float* __restrict__ img,
                                              ushort_t* __restrict__ qb,
                                              int4* __restrict__ ib) {
  const int blk = (int)blockIdx.x;
  const int tid = (int)threadIdx.x;
  if (blk < 2048) {
    const int t = blk * 256 + tid;
    const float4 v = ((const float4*)qry)[t];
    ushort4 o;
    o.x = f2bf(v.x); o.y = f2bf(v.y); o.z = f2bf(v.z); o.w = f2bf(v.w);
    ((ushort4*)qb)[t] = o;
  } else {
    const int tg = blk - 2048;
    const int b = tg >> 8;
    const int tile = tg & 255;
    __shared__ __align__(16) ushort_t T[32 * 128];
    {
      const int r = tid >> 3;
      const int seg = tid & 7;
      const float* src = img + ((size_t)(b * NM + tile * 32 + r)) * KD + seg * 16;
      ushort_t tmp[16];
#pragma unroll
      for (int i = 0; i < 4; ++i) {
        const float4 v = ((const float4*)src)[i];
        tmp[i * 4 + 0] = f2bf(v.x);
        tmp[i * 4 + 1] = f2bf(v.y);
        tmp[i * 4 + 2] = f2bf(v.z);
        tmp[i * 4 + 3] = f2bf(v.w);
      }
      const int c0 = (seg * 16 + r * 8) & 127;
      const int c1 = (seg * 16 + 8 + r * 8) & 127;
      *(int4*)&T[r * 128 + c0] = *(const int4*)&tmp[0];
      *(int4*)&T[r * 128 + c1] = *(const int4*)&tmp[8];
    }
    __syncthreads();
    int4* dstt = ib + ((size_t)b * 256 + tile) * 512;
#pragma unroll
    for (int h = 0; h < 2; ++h) {
      const int n = tid + h * 256;
      const int l = n & 63;
      const int ks = (n >> 6) & 3;
      const int htl = n >> 8;
      const int row = htl * 16 + (l & 15);
      const int col = ks * 32 + (l >> 4) * 8;
      dstt[n] = *(const int4*)&T[row * 128 + ((col + row * 8) & 127)];
    }
  }
}

// ---------------- Fallback K1: R8's proven kernel ----------------
__global__ __launch_bounds__(512, 1) void wr_mfma8(const float* __restrict__ qry,
                                                   const float* __restrict__ img,
                                                   const ushort_t* __restrict__ qb,
                                                   const int4* __restrict__ ib,
                                                   int* __restrict__ out) {
  const int bid = (int)blockIdx.x;
  const int b = (bid & 7) >> 1;
  const int qt = ((bid >> 3) << 1) | (bid & 1);
  const int qbase = qt * 64;

  const int tid = (int)threadIdx.x;
  const int lane = tid & 63;
  const int w = tid >> 6;
  const int q15 = lane & 15;
  const int quad = lane >> 4;

  const ushort_t* Qb = qb + ((size_t)b * NQ + qbase) * KD;
  const int4* ibc = ib + (size_t)b * 131072;

  bf16x8 bfrag[4][4];
#pragma unroll
  for (int s = 0; s < 4; ++s)
#pragma unroll
    for (int ks = 0; ks < 4; ++ks)
      bfrag[s][ks] =
          *(const bf16x8*)(Qb + (size_t)(s * 16 + q15) * KD + ks * 32 + quad * 8);

  float tch[4][4];
#pragma unroll
  for (int s = 0; s < 4; ++s)
#pragma unroll
    for (int e = 0; e < 4; ++e) tch[s][e] = -FLT_MAX;

  bf16x8 B0[4], B1[4], B2[4];

  auto loadH = [&](bf16x8* R, int h) {
    const int4* p = ibc + (((w * 64 + h) << 8) + lane);
#pragma unroll
    for (int ks = 0; ks < 4; ++ks) R[ks] = *(const bf16x8*)(p + ks * 64);
  };

  int hl = 3;
  int vb = 2047 - 4 * quad;

  auto step = [&](bf16x8* R) {
    f32x4 a[4];
#pragma unroll
    for (int s = 0; s < 4; ++s) a[s] = {0.f, 0.f, 0.f, 0.f};
#pragma unroll
    for (int ks = 0; ks < 4; ++ks)
#pragma unroll
      for (int s = 0; s < 4; ++s)
        a[s] = __builtin_amdgcn_mfma_f32_16x16x32_bf16(R[ks], bfrag[s][ks], a[s],
                                                       0, 0, 0);
    if (hl < 64) loadH(R, hl);
    ++hl;
#pragma unroll
    for (int s = 0; s < 4; ++s) {
#pragma unroll
      for (int r = 0; r < 4; ++r) {
        const unsigned kr = (unsigned)(vb - r);
        const float k =
            __uint_as_float((__float_as_uint(a[s][r]) & 0xFFFFF800u) | kr);
        tch[s][3] = fmed3(k, tch[s][2], tch[s][3]);
        tch[s][2] = fmed3(k, tch[s][1], tch[s][2]);
        tch[s][1] = fmed3(k, tch[s][0], tch[s][1]);
        tch[s][0] = fmaxf(tch[s][0], k);
      }
    }
    vb -= 16;
  };

  loadH(B0, 0);
  loadH(B1, 1);
  loadH(B2, 2);
  for (int g = 0; g < 21; ++g) { step(B0); step(B1); step(B2); }
  step(B0);

#pragma unroll
  for (int s = 0; s < 4; ++s) {
    float k4[4];
#pragma unroll
    for (int e = 0; e < 4; ++e) k4[e] = __shfl_down(tch[s][e], 32, 64);
#pragma unroll
    for (int e = 0; e < 4; ++e) {
      const float k = k4[e];
      tch[s][3] = fmed3(k, tch[s][2], tch[s][3]);
      tch[s][2] = fmed3(k, tch[s][1], tch[s][2]);
      tch[s][1] = fmed3(k, tch[s][0], tch[s][1]);
      tch[s][0] = fmaxf(tch[s][0], k);
    }
#pragma unroll
    for (int e = 0; e < 4; ++e) k4[e] = __shfl_down(tch[s][e], 16, 64);
#pragma unroll
    for (int e = 0; e < 4; ++e) {
      const float k = k4[e];
      tch[s][3] = fmed3(k, tch[s][2], tch[s][3]);
      tch[s][2] = fmed3(k, tch[s][1], tch[s][2]);
      tch[s][1] = fmed3(k, tch[s][0], tch[s][1]);
      tch[s][0] = fmaxf(tch[s][0], k);
    }
  }

  __shared__ float ck[64][33];
  __shared__ int top8[64][8];
  __shared__ double pd[64][8];
  __shared__ int pi[64][8];

  if (lane < 16) {
#pragma unroll
    for (int s = 0; s < 4; ++s)
#pragma unroll
      for (int e = 0; e < 4; ++e) ck[s * 16 + q15][w * 4 + e] = tch[s][e];
  }
  __syncthreads();

  for (int p = tid; p < 2048; p += 512) {
    const int q = p >> 5;
    const int j = p & 31;
    const float k = ck[q][j];
    int rank = 0;
#pragma unroll 8
    for (int i = 0; i < 32; ++i) {
      const float o = ck[q][i];
      rank += (o > k) || (o == k && i < j);
    }
    if (rank < 8) {
      const unsigned bits = __float_as_uint(k);
      top8[q][rank] = (j >> 2) * 1024 + 2047 - (int)(bits & 0x7FFu);
    }
  }
  __syncthreads();

  {
    const int q = tid >> 3;
    const int slot = tid & 7;
    const int m = top8[q][slot];
    const float* qrow = qry + ((size_t)b * NQ + qbase + q) * KD;
    const float* irow = img + ((size_t)b * NM + m) * KD;
    double s0 = 0.0, s1 = 0.0, s2 = 0.0, s3 = 0.0;
#pragma unroll
    for (int k = 0; k < KD; k += 4) {
      const float4 xv = *(const float4*)(qrow + k);
      const float4 yv = *(const float4*)(irow + k);
      s0 = fma((double)xv.x, (double)yv.x, s0);
      s1 = fma((double)xv.y, (double)yv.y, s1);
      s2 = fma((double)xv.z, (double)yv.z, s2);
      s3 = fma((double)xv.w, (double)yv.w, s3);
    }
    pd[q][slot] = (s0 + s1) + (s2 + s3);
    pi[q][slot] = m;
  }
  __syncthreads();

  if (tid < 64) {
    const int q = tid;
    double fv[4];
    int fi[4];
#pragma unroll
    for (int e = 0; e < 4; ++e) { fv[e] = -DBL_MAX; fi[e] = 0x7fffffff; }
    for (int sl = 0; sl < 8; ++sl) {
      const double v = pd[q][sl];
      const int m = pi[q][sl];
      const bool b0 = BETTER64(v, m, fv[0], fi[0]);
      const bool b1 = BETTER64(v, m, fv[1], fi[1]);
      const bool b2 = BETTER64(v, m, fv[2], fi[2]);
      const bool b3 = BETTER64(v, m, fv[3], fi[3]);
      fv[3] = b2 ? fv[2] : (b3 ? v : fv[3]);
      fi[3] = b2 ? fi[2] : (b3 ? m : fi[3]);
      fv[2] = b1 ? fv[1] : (b2 ? v : fv[2]);
      fi[2] = b1 ? fi[1] : (b2 ? m : fi[2]);
      fv[1] = b0 ? fv[0] : (b1 ? v : fv[1]);
      fi[1] = b0 ? fi[0] : (b1 ? m : fi[1]);
      fv[0] = b0 ? v : fv[0];
      fi[0] = b0 ? m : fi[0];
    }
    int4 o;
    o.x = fi[0]; o.y = fi[1]; o.z = fi[2]; o.w = fi[3];
    *(int4*)(out + ((size_t)b * NQ + qbase + q) * 4) = o;
  }
}

// ---------------- Tier-3: fp32 LDS-tiled fallback ----------------
#define QT 64
#define MT 128
#define KC 64
#define NTHREADS 512

__global__ __launch_bounds__(NTHREADS) void wr_main(const float* __restrict__ qry,
                                                    const float* __restrict__ img,
                                                    int* __restrict__ out) {
  __shared__ __align__(16) float A_lds[KD * QT];
  __shared__ __align__(16) float B_lds[KC * MT];

  const int t = (int)threadIdx.x;
  const int b = (int)blockIdx.x >> 6;
  const int qbase = ((int)blockIdx.x & 63) * QT;

  const float* qp = qry + ((size_t)b * NQ + qbase) * KD;
  const float* ip = img + (size_t)b * NM * KD;

  {
    const int r = t >> 3;
    const int kc = t & 7;
    const float* src = qp + (size_t)r * KD;
#pragma unroll
    for (int i = 0; i < 4; ++i) {
      const int k0 = kc * 4 + i * 32;
      const float4 v = *(const float4*)(src + k0);
      A_lds[(k0 + 0) * QT + r] = v.x;
      A_lds[(k0 + 1) * QT + r] = v.y;
      A_lds[(k0 + 2) * QT + r] = v.z;
      A_lds[(k0 + 3) * QT + r] = v.w;
    }
  }

  const int qi = t >> 5;
  const int mi = t & 31;

  float tv[4][4];
  int ti[4][4];
#pragma unroll
  for (int j = 0; j < 4; ++j)
#pragma unroll
    for (int s = 0; s < 4; ++s) { tv[j][s] = -FLT_MAX; ti[j][s] = 0x7fffffff; }

  for (int tile = 0; tile < NM / MT; ++tile) {
    const int mbase = tile * MT;
    float acc[4][4];
#pragma unroll
    for (int j = 0; j < 4; ++j)
#pragma unroll
      for (int s = 0; s < 4; ++s) acc[j][s] = 0.0f;

    for (int kb = 0; kb < KD; kb += KC) {
      __syncthreads();
      {
        const int r = t >> 2;
        const int kc = t & 3;
        const float* src = ip + (size_t)(mbase + r) * KD + kb;
#pragma unroll
        for (int i = 0; i < 4; ++i) {
          const int k0 = kc * 4 + i * 16;
          const float4 v = *(const float4*)(src + k0);
          B_lds[(k0 + 0) * MT + r] = v.x;
          B_lds[(k0 + 1) * MT + r] = v.y;
          B_lds[(k0 + 2) * MT + r] = v.z;
          B_lds[(k0 + 3) * MT + r] = v.w;
        }
      }
      __syncthreads();

#pragma unroll 8
      for (int k = 0; k < KC; ++k) {
        const float4 av = *(const float4*)&A_lds[(kb + k) * QT + qi * 4];
        const float4 bv = *(const float4*)&B_lds[k * MT + mi * 4];
        acc[0][0] = fmaf(av.x, bv.x, acc[0][0]);
        acc[0][1] = fmaf(av.x, bv.y, acc[0][1]);
        acc[0][2] = fmaf(av.x, bv.z, acc[0][2]);
        acc[0][3] = fmaf(av.x, bv.w, acc[0][3]);
        acc[1][0] = fmaf(av.y, bv.x, acc[1][0]);
        acc[1][1] = fmaf(av.y, bv.y, acc[1][1]);
        acc[1][2] = fmaf(av.y, bv.z, acc[1][2]);
        acc[1][3] = fmaf(av.y, bv.w, acc[1][3]);
        acc[2][0] = fmaf(av.z, bv.x, acc[2][0]);
        acc[2][1] = fmaf(av.z, bv.y, acc[2][1]);
        acc[2][2] = fmaf(av.z, bv.z, acc[2][2]);
        acc[2][3] = fmaf(av.z, bv.w, acc[2][3]);
        acc[3][0] = fmaf(av.w, bv.x, acc[3][0]);
        acc[3][1] = fmaf(av.w, bv.y, acc[3][1]);
        acc[3][2] = fmaf(av.w, bv.z, acc[3][2]);
        acc[3][3] = fmaf(av.w, bv.w, acc[3][3]);
      }
    }

#pragma unroll
    for (int j = 0; j < 4; ++j) {
#pragma unroll
      for (int s = 0; s < 4; ++s) {
        const float v = acc[j][s];
        const int m = mbase + mi * 4 + s;
        const bool b0 = v > tv[j][0];
        const bool b1 = v > tv[j][1];
        const bool b2 = v > tv[j][2];
        const bool b3 = v > tv[j][3];
        tv[j][3] = b2 ? tv[j][2] : (b3 ? v : tv[j][3]);
        ti[j][3] = b2 ? ti[j][2] : (b3 ? m : ti[j][3]);
        tv[j][2] = b1 ? tv[j][1] : (b2 ? v : tv[j][2]);
        ti[j][2] = b1 ? ti[j][1] : (b2 ? m : ti[j][2]);
        tv[j][1] = b0 ? tv[j][0] : (b1 ? v : tv[j][1]);
        ti[j][1] = b0 ? ti[j][0] : (b1 ? m : ti[j][1]);
        tv[j][0] = b0 ? v : tv[j][0];
        ti[j][0] = b0 ? m : ti[j][0];
      }
    }
  }

  __syncthreads();
  int* idx_lds = (int*)B_lds;
#pragma unroll
  for (int j = 0; j < 4; ++j)
#pragma unroll
    for (int s = 0; s < 4; ++s)
      idx_lds[(qi * 4 + j) * 128 + mi * 4 + s] = ti[j][s];
  __syncthreads();

  double* pv = (double*)A_lds;
  int* piL = (int*)(A_lds + 4096);
  {
    const int r = t >> 3;
    const int slot = t & 7;
    const float* qrow = qp + (size_t)r * KD;
    double bv[4];
    int bi[4];
#pragma unroll
    for (int e = 0; e < 4; ++e) { bv[e] = -DBL_MAX; bi[e] = 0x7fffffff; }

    for (int c = 0; c < 16; ++c) {
      const int m = idx_lds[r * 128 + slot * 16 + c];
      const float* irow = ip + (size_t)m * KD;
      double s0 = 0.0, s1 = 0.0, s2 = 0.0, s3 = 0.0;
#pragma unroll
      for (int k = 0; k < KD; k += 4) {
        const float4 xv = *(const float4*)(qrow + k);
        const float4 yv = *(const float4*)(irow + k);
        s0 = fma((double)xv.x, (double)yv.x, s0);
        s1 = fma((double)xv.y, (double)yv.y, s1);
        s2 = fma((double)xv.z, (double)yv.z, s2);
        s3 = fma((double)xv.w, (double)yv.w, s3);
      }
      const double v = (s0 + s1) + (s2 + s3);
      const bool b0 = BETTER64(v, m, bv[0], bi[0]);
      const bool b1 = BETTER64(v, m, bv[1], bi[1]);
      const bool b2 = BETTER64(v, m, bv[2], bi[2]);
      const bool b3 = BETTER64(v, m, bv[3], bi[3]);
      bv[3] = b2 ? bv[2] : (b3 ? v : bv[3]);
      bi[3] = b2 ? bi[2] : (b3 ? m : bi[3]);
      bv[2] = b1 ? bv[1] : (b2 ? v : bv[2]);
      bi[2] = b1 ? bi[1] : (b2 ? m : bi[2]);
      bv[1] = b0 ? bv[0] : (b1 ? v : bv[1]);
      bi[1] = b0 ? bi[0] : (b1 ? m : bi[1]);
      bv[0] = b0 ? v : bv[0];
      bi[0] = b0 ? m : bi[0];
    }
#pragma unroll
    for (int e = 0; e < 4; ++e) {
      pv[t * 4 + e] = bv[e];
      piL[t * 4 + e] = bi[e];
    }
  }
  __syncthreads();

  if (t < QT) {
    double fv[4];
    int fi[4];
#pragma unroll
    for (int e = 0; e < 4; ++e) { fv[e] = -DBL_MAX; fi[e] = 0x7fffffff; }
    for (int sl = 0; sl < 8; ++sl) {
#pragma unroll
      for (int e = 0; e < 4; ++e) {
        const double v = pv[(t * 8 + sl) * 4 + e];
        const int m = piL[(t * 8 + sl) * 4 + e];
        const bool b0 = BETTER64(v, m, fv[0], fi[0]);
        const bool b1 = BETTER64(v, m, fv[1], fi[1]);
        const bool b2 = BETTER64(v, m, fv[2], fi[2]);
        const bool b3 = BETTER64(v, m, fv[3], fi[3]);
        fv[3] = b2 ? fv[2] : (b3 ? v : fv[3]);
        fi[3] = b2 ? fi[2] : (b3 ? m : fi[3]);
        fv[2] = b1 ? fv[1] : (b2 ? v : fv[2]);
        fi[2] = b1 ? fi[1] : (b2 ? m : fi[2]);
        fv[1] = b0 ? fv[0] : (b1 ? v : fv[1]);
        fi[1] = b0 ? fi[0] : (b1 ? m : fi[1]);
        fv[0] = b0 ? v : fv[0];
        fi[0] = b0 ? m : fi[0];
      }
    }
    int4 o;
    o.x = fi[0]; o.y = fi[1]; o.z = fi[2]; o.w = fi[3];
    *(int4*)(out + ((size_t)b * NQ + qbase + t) * 4) = o;
  }
}

extern "C" void kernel_launch(void* const* d_in, const int* in_sizes, int n_in,
                              void* d_out, int out_size, void* d_ws, size_t ws_size,
                              hipStream_t stream) {
  const float* qry = (const float*)d_in[0];  // (4, 4096, 128) fp32
  const float* img = (const float*)d_in[1];  // (4, 8192, 128) fp32
  int* out = (int*)d_out;                    // (4, 4096, 4) int32

  const size_t qbBytes = (size_t)NBATCH * NQ * KD * sizeof(ushort_t);  // 4 MB
  const size_t ibBytes = (size_t)NBATCH * NM * KD * sizeof(ushort_t);  // 8 MB

  if (ws_size >= qbBytes + ibBytes) {
    ushort_t* qb = (ushort_t*)d_ws;
    int4* ib = (int4*)((char*)d_ws + qbBytes);
    void* args[] = {(void*)&qry, (void*)&img, (void*)&qb, (void*)&ib, (void*)&out};
    hipError_t e = hipLaunchCooperativeKernel((const void*)wr_fused, dim3(256),
                                              dim3(512), args, 0, stream);
    if (e != hipSuccess) {
      // proven R8 two-kernel path
      wr_cvt<<<3072, 256, 0, stream>>>(qry, img, qb, ib);
      wr_mfma8<<<256, 512, 0, stream>>>(qry, img, qb, ib, out);
    }
  } else {
    wr_main<<<NBATCH * (NQ / QT), NTHREADS, 0, stream>>>(qry, img, out);
  }
}

// Round 12
// 133.090 us; speedup vs baseline: 1.4991x; 1.4991x over previous
//
#include <hip/hip_runtime.h>
#include <float.h>
#include <stdint.h>

// WindowRouting: out[b][q][0..3] = indices of top-4 of (Q[b,q,:] . I[b,m,:]) over m.
// Scale dropped (order-preserving).
//
// R11 LESSON: cooperative fusion regressed both the kernel (grid.sync +
// 256-block phase-1) and the gap (~62 us is FIXED harness cost, not
// per-dispatch). Structure reverted to the proven R8 two-kernel path.
// R12 change: the per-score top-4 insert chain is split 2-way per strip
// (r{0,1} vs r{2,3}) -> 8 independent chains, halving the score->score
// dependency depth in the VALU tail. Chains merged lane-locally at the end
// (top-4 of union of two top-4s — proven R2 merge pattern), then the
// existing quad-tree shfl merge (snapshot-first, R4 lesson).
//
// K0 wr_cvt: fp32->bf16; image LDS-transposed to 16x16x32-fragment-linear.
// K1 wr_mfma8: 256 blocks x 512 thr; block = 64 q x all m; wave = m-eighth;
//   bfrag (4 strips of 16 q) pinned; 3-deep image ring; packed keys
//   (low 11 bits = 2047 - m_local); per-sixteenth... (per-eighth) top-4 ->
//   32 cand/row -> rank top-8 -> fp64 refine vs fp32 originals -> exact top-4.
// Tier-3: fp32 LDS fallback.

#define NBATCH 4
#define NQ 4096
#define NM 8192
#define KD 128

typedef unsigned short ushort_t;
typedef __attribute__((ext_vector_type(8))) short bf16x8;
typedef __attribute__((ext_vector_type(4))) float f32x4;

#define BETTER64(v, i, w, j) (((v) > (w)) || ((v) == (w) && (i) < (j)))

__device__ inline float fmed3(float a, float b, float c) {
#if __has_builtin(__builtin_amdgcn_fmed3f)
  return __builtin_amdgcn_fmed3f(a, b, c);
#else
  return fmaxf(fminf(a, b), fminf(fmaxf(a, b), c));
#endif
}

__device__ inline ushort_t f2bf(float f) {
  unsigned u = __float_as_uint(f);
  u += 0x7fffu + ((u >> 16) & 1u);  // RNE
  return (ushort_t)(u >> 16);
}

// ---------------- K0: convert + swizzle (proven R7/R8) ----------------
__global__ __launch_bounds__(256) void wr_cvt(const float* __restrict__ qry,
                                              const float* __restrict__ img,
                                              ushort_t* __restrict__ qb,
                                              int4* __restrict__ ib) {
  const int blk = (int)blockIdx.x;
  const int tid = (int)threadIdx.x;
  if (blk < 2048) {
    const int t = blk * 256 + tid;
    const float4 v = ((const float4*)qry)[t];
    ushort4 o;
    o.x = f2bf(v.x); o.y = f2bf(v.y); o.z = f2bf(v.z); o.w = f2bf(v.w);
    ((ushort4*)qb)[t] = o;
  } else {
    const int tg = blk - 2048;
    const int b = tg >> 8;
    const int tile = tg & 255;
    __shared__ __align__(16) ushort_t T[32 * 128];
    {
      const int r = tid >> 3;
      const int seg = tid & 7;
      const float* src = img + ((size_t)(b * NM + tile * 32 + r)) * KD + seg * 16;
      ushort_t tmp[16];
#pragma unroll
      for (int i = 0; i < 4; ++i) {
        const float4 v = ((const float4*)src)[i];
        tmp[i * 4 + 0] = f2bf(v.x);
        tmp[i * 4 + 1] = f2bf(v.y);
        tmp[i * 4 + 2] = f2bf(v.z);
        tmp[i * 4 + 3] = f2bf(v.w);
      }
      const int c0 = (seg * 16 + r * 8) & 127;
      const int c1 = (seg * 16 + 8 + r * 8) & 127;
      *(int4*)&T[r * 128 + c0] = *(const int4*)&tmp[0];
      *(int4*)&T[r * 128 + c1] = *(const int4*)&tmp[8];
    }
    __syncthreads();
    int4* dstt = ib + ((size_t)b * 256 + tile) * 512;
#pragma unroll
    for (int h = 0; h < 2; ++h) {
      const int n = tid + h * 256;
      const int l = n & 63;
      const int ks = (n >> 6) & 3;
      const int htl = n >> 8;
      const int row = htl * 16 + (l & 15);
      const int col = ks * 32 + (l >> 4) * 8;
      dstt[n] = *(const int4*)&T[row * 128 + ((col + row * 8) & 127)];
    }
  }
}

// ---------------- K1: MFMA screen + fp64 refine (R8 + split chains) ----------
__global__ __launch_bounds__(512, 1) void wr_mfma8(const float* __restrict__ qry,
                                                   const float* __restrict__ img,
                                                   const ushort_t* __restrict__ qb,
                                                   const int4* __restrict__ ib,
                                                   int* __restrict__ out) {
  const int bid = (int)blockIdx.x;               // 0..255
  const int b = (bid & 7) >> 1;                  // batch pinned to XCD pair
  const int qt = ((bid >> 3) << 1) | (bid & 1);  // 0..63
  const int qbase = qt * 64;

  const int tid = (int)threadIdx.x;
  const int lane = tid & 63;
  const int w = tid >> 6;      // 0..7 -> m-eighth (64 half-tiles of 16 m)
  const int q15 = lane & 15;
  const int quad = lane >> 4;  // 0..3

  const ushort_t* Qb = qb + ((size_t)b * NQ + qbase) * KD;
  const int4* ibc = ib + (size_t)b * 131072;

  bf16x8 bfrag[4][4];  // 4 strips of 16 q, pinned (64 VGPRs)
#pragma unroll
  for (int s = 0; s < 4; ++s)
#pragma unroll
    for (int ks = 0; ks < 4; ++ks)
      bfrag[s][ks] =
          *(const bf16x8*)(Qb + (size_t)(s * 16 + q15) * KD + ks * 32 + quad * 8);

  // 8 independent top-4 chains: tA[s] takes r=0,1; tB[s] takes r=2,3
  float tA[4][4], tB[4][4];
#pragma unroll
  for (int s = 0; s < 4; ++s)
#pragma unroll
    for (int e = 0; e < 4; ++e) { tA[s][e] = -FLT_MAX; tB[s][e] = -FLT_MAX; }

  bf16x8 B0[4], B1[4], B2[4];  // 3-deep ring

  auto loadH = [&](bf16x8* R, int h) {
    const int4* p = ibc + (((w * 64 + h) << 8) + lane);
#pragma unroll
    for (int ks = 0; ks < 4; ++ks) R[ks] = *(const bf16x8*)(p + ks * 64);
  };

  int hl = 3;
  int vb = 2047 - 4 * quad;  // m_local = 16*h + 4*quad + r (< 1024)

  auto step = [&](bf16x8* R) {
    f32x4 a[4];
#pragma unroll
    for (int s = 0; s < 4; ++s) a[s] = {0.f, 0.f, 0.f, 0.f};
#pragma unroll
    for (int ks = 0; ks < 4; ++ks)
#pragma unroll
      for (int s = 0; s < 4; ++s)
        a[s] = __builtin_amdgcn_mfma_f32_16x16x32_bf16(R[ks], bfrag[s][ks], a[s],
                                                       0, 0, 0);
    if (hl < 64) loadH(R, hl);
    ++hl;
#pragma unroll
    for (int s = 0; s < 4; ++s) {
      // chain A: r = 0, 1
      {
        const float k0 =
            __uint_as_float((__float_as_uint(a[s][0]) & 0xFFFFF800u) |
                            (unsigned)vb);
        tA[s][3] = fmed3(k0, tA[s][2], tA[s][3]);
        tA[s][2] = fmed3(k0, tA[s][1], tA[s][2]);
        tA[s][1] = fmed3(k0, tA[s][0], tA[s][1]);
        tA[s][0] = fmaxf(tA[s][0], k0);
        const float k1 =
            __uint_as_float((__float_as_uint(a[s][1]) & 0xFFFFF800u) |
                            (unsigned)(vb - 1));
        tA[s][3] = fmed3(k1, tA[s][2], tA[s][3]);
        tA[s][2] = fmed3(k1, tA[s][1], tA[s][2]);
        tA[s][1] = fmed3(k1, tA[s][0], tA[s][1]);
        tA[s][0] = fmaxf(tA[s][0], k1);
      }
      // chain B: r = 2, 3 (independent of chain A -> 2x ILP)
      {
        const float k2 =
            __uint_as_float((__float_as_uint(a[s][2]) & 0xFFFFF800u) |
                            (unsigned)(vb - 2));
        tB[s][3] = fmed3(k2, tB[s][2], tB[s][3]);
        tB[s][2] = fmed3(k2, tB[s][1], tB[s][2]);
        tB[s][1] = fmed3(k2, tB[s][0], tB[s][1]);
        tB[s][0] = fmaxf(tB[s][0], k2);
        const float k3 =
            __uint_as_float((__float_as_uint(a[s][3]) & 0xFFFFF800u) |
                            (unsigned)(vb - 3));
        tB[s][3] = fmed3(k3, tB[s][2], tB[s][3]);
        tB[s][2] = fmed3(k3, tB[s][1], tB[s][2]);
        tB[s][1] = fmed3(k3, tB[s][0], tB[s][1]);
        tB[s][0] = fmaxf(tB[s][0], k3);
      }
    }
    vb -= 16;
  };

  loadH(B0, 0);
  loadH(B1, 1);
  loadH(B2, 2);
  for (int g = 0; g < 21; ++g) { step(B0); step(B1); step(B2); }
  step(B0);  // half-tile 63

  // merge chain B into chain A (lane-local, disjoint sets -> top-4 of union)
#pragma unroll
  for (int s = 0; s < 4; ++s) {
#pragma unroll
    for (int e = 0; e < 4; ++e) {
      const float k = tB[s][e];
      tA[s][3] = fmed3(k, tA[s][2], tA[s][3]);
      tA[s][2] = fmed3(k, tA[s][1], tA[s][2]);
      tA[s][1] = fmed3(k, tA[s][0], tA[s][1]);
      tA[s][0] = fmaxf(tA[s][0], k);
    }
  }

  // quad-tree merge (snapshot donor regs BEFORE mutating — R4 lesson)
#pragma unroll
  for (int s = 0; s < 4; ++s) {
    float k4[4];
#pragma unroll
    for (int e = 0; e < 4; ++e) k4[e] = __shfl_down(tA[s][e], 32, 64);
#pragma unroll
    for (int e = 0; e < 4; ++e) {
      const float k = k4[e];
      tA[s][3] = fmed3(k, tA[s][2], tA[s][3]);
      tA[s][2] = fmed3(k, tA[s][1], tA[s][2]);
      tA[s][1] = fmed3(k, tA[s][0], tA[s][1]);
      tA[s][0] = fmaxf(tA[s][0], k);
    }
#pragma unroll
    for (int e = 0; e < 4; ++e) k4[e] = __shfl_down(tA[s][e], 16, 64);
#pragma unroll
    for (int e = 0; e < 4; ++e) {
      const float k = k4[e];
      tA[s][3] = fmed3(k, tA[s][2], tA[s][3]);
      tA[s][2] = fmed3(k, tA[s][1], tA[s][2]);
      tA[s][1] = fmed3(k, tA[s][0], tA[s][1]);
      tA[s][0] = fmaxf(tA[s][0], k);
    }
  }

  __shared__ float ck[64][33];
  __shared__ int top8[64][8];
  __shared__ double pd[64][8];
  __shared__ int pi[64][8];

  if (lane < 16) {
#pragma unroll
    for (int s = 0; s < 4; ++s)
#pragma unroll
      for (int e = 0; e < 4; ++e) ck[s * 16 + q15][w * 4 + e] = tA[s][e];
  }
  __syncthreads();

  // rank-select top-8 of 32 packed keys per row (ranks unique)
  for (int p = tid; p < 2048; p += 512) {
    const int q = p >> 5;
    const int j = p & 31;
    const float k = ck[q][j];
    int rank = 0;
#pragma unroll 8
    for (int i = 0; i < 32; ++i) {
      const float o = ck[q][i];
      rank += (o > k) || (o == k && i < j);
    }
    if (rank < 8) {
      const unsigned bits = __float_as_uint(k);
      top8[q][rank] = (j >> 2) * 1024 + 2047 - (int)(bits & 0x7FFu);
    }
  }
  __syncthreads();

  // fp64 refine: one candidate per thread
  {
    const int q = tid >> 3;
    const int slot = tid & 7;
    const int m = top8[q][slot];
    const float* qrow = qry + ((size_t)b * NQ + qbase + q) * KD;
    const float* irow = img + ((size_t)b * NM + m) * KD;
    double s0 = 0.0, s1 = 0.0, s2 = 0.0, s3 = 0.0;
#pragma unroll
    for (int k = 0; k < KD; k += 4) {
      const float4 xv = *(const float4*)(qrow + k);
      const float4 yv = *(const float4*)(irow + k);
      s0 = fma((double)xv.x, (double)yv.x, s0);
      s1 = fma((double)xv.y, (double)yv.y, s1);
      s2 = fma((double)xv.z, (double)yv.z, s2);
      s3 = fma((double)xv.w, (double)yv.w, s3);
    }
    pd[q][slot] = (s0 + s1) + (s2 + s3);
    pi[q][slot] = m;
  }
  __syncthreads();

  // exact top-4 of 8 refined, (value desc, index asc)
  if (tid < 64) {
    const int q = tid;
    double fv[4];
    int fi[4];
#pragma unroll
    for (int e = 0; e < 4; ++e) { fv[e] = -DBL_MAX; fi[e] = 0x7fffffff; }
    for (int sl = 0; sl < 8; ++sl) {
      const double v = pd[q][sl];
      const int m = pi[q][sl];
      const bool b0 = BETTER64(v, m, fv[0], fi[0]);
      const bool b1 = BETTER64(v, m, fv[1], fi[1]);
      const bool b2 = BETTER64(v, m, fv[2], fi[2]);
      const bool b3 = BETTER64(v, m, fv[3], fi[3]);
      fv[3] = b2 ? fv[2] : (b3 ? v : fv[3]);
      fi[3] = b2 ? fi[2] : (b3 ? m : fi[3]);
      fv[2] = b1 ? fv[1] : (b2 ? v : fv[2]);
      fi[2] = b1 ? fi[1] : (b2 ? m : fi[2]);
      fv[1] = b0 ? fv[0] : (b1 ? v : fv[1]);
      fi[1] = b0 ? fi[0] : (b1 ? m : fi[1]);
      fv[0] = b0 ? v : fv[0];
      fi[0] = b0 ? m : fi[0];
    }
    int4 o;
    o.x = fi[0]; o.y = fi[1]; o.z = fi[2]; o.w = fi[3];
    *(int4*)(out + ((size_t)b * NQ + qbase + q) * 4) = o;
  }
}

// ---------------- Tier-3: fp32 LDS-tiled fallback ----------------
#define QT 64
#define MT 128
#define KC 64
#define NTHREADS 512

__global__ __launch_bounds__(NTHREADS) void wr_main(const float* __restrict__ qry,
                                                    const float* __restrict__ img,
                                                    int* __restrict__ out) {
  __shared__ __align__(16) float A_lds[KD * QT];
  __shared__ __align__(16) float B_lds[KC * MT];

  const int t = (int)threadIdx.x;
  const int b = (int)blockIdx.x >> 6;
  const int qbase = ((int)blockIdx.x & 63) * QT;

  const float* qp = qry + ((size_t)b * NQ + qbase) * KD;
  const float* ip = img + (size_t)b * NM * KD;

  {
    const int r = t >> 3;
    const int kc = t & 7;
    const float* src = qp + (size_t)r * KD;
#pragma unroll
    for (int i = 0; i < 4; ++i) {
      const int k0 = kc * 4 + i * 32;
      const float4 v = *(const float4*)(src + k0);
      A_lds[(k0 + 0) * QT + r] = v.x;
      A_lds[(k0 + 1) * QT + r] = v.y;
      A_lds[(k0 + 2) * QT + r] = v.z;
      A_lds[(k0 + 3) * QT + r] = v.w;
    }
  }

  const int qi = t >> 5;
  const int mi = t & 31;

  float tv[4][4];
  int ti[4][4];
#pragma unroll
  for (int j = 0; j < 4; ++j)
#pragma unroll
    for (int s = 0; s < 4; ++s) { tv[j][s] = -FLT_MAX; ti[j][s] = 0x7fffffff; }

  for (int tile = 0; tile < NM / MT; ++tile) {
    const int mbase = tile * MT;
    float acc[4][4];
#pragma unroll
    for (int j = 0; j < 4; ++j)
#pragma unroll
      for (int s = 0; s < 4; ++s) acc[j][s] = 0.0f;

    for (int kb = 0; kb < KD; kb += KC) {
      __syncthreads();
      {
        const int r = t >> 2;
        const int kc = t & 3;
        const float* src = ip + (size_t)(mbase + r) * KD + kb;
#pragma unroll
        for (int i = 0; i < 4; ++i) {
          const int k0 = kc * 4 + i * 16;
          const float4 v = *(const float4*)(src + k0);
          B_lds[(k0 + 0) * MT + r] = v.x;
          B_lds[(k0 + 1) * MT + r] = v.y;
          B_lds[(k0 + 2) * MT + r] = v.z;
          B_lds[(k0 + 3) * MT + r] = v.w;
        }
      }
      __syncthreads();

#pragma unroll 8
      for (int k = 0; k < KC; ++k) {
        const float4 av = *(const float4*)&A_lds[(kb + k) * QT + qi * 4];
        const float4 bv = *(const float4*)&B_lds[k * MT + mi * 4];
        acc[0][0] = fmaf(av.x, bv.x, acc[0][0]);
        acc[0][1] = fmaf(av.x, bv.y, acc[0][1]);
        acc[0][2] = fmaf(av.x, bv.z, acc[0][2]);
        acc[0][3] = fmaf(av.x, bv.w, acc[0][3]);
        acc[1][0] = fmaf(av.y, bv.x, acc[1][0]);
        acc[1][1] = fmaf(av.y, bv.y, acc[1][1]);
        acc[1][2] = fmaf(av.y, bv.z, acc[1][2]);
        acc[1][3] = fmaf(av.y, bv.w, acc[1][3]);
        acc[2][0] = fmaf(av.z, bv.x, acc[2][0]);
        acc[2][1] = fmaf(av.z, bv.y, acc[2][1]);
        acc[2][2] = fmaf(av.z, bv.z, acc[2][2]);
        acc[2][3] = fmaf(av.z, bv.w, acc[2][3]);
        acc[3][0] = fmaf(av.w, bv.x, acc[3][0]);
        acc[3][1] = fmaf(av.w, bv.y, acc[3][1]);
        acc[3][2] = fmaf(av.w, bv.z, acc[3][2]);
        acc[3][3] = fmaf(av.w, bv.w, acc[3][3]);
      }
    }

#pragma unroll
    for (int j = 0; j < 4; ++j) {
#pragma unroll
      for (int s = 0; s < 4; ++s) {
        const float v = acc[j][s];
        const int m = mbase + mi * 4 + s;
        const bool b0 = v > tv[j][0];
        const bool b1 = v > tv[j][1];
        const bool b2 = v > tv[j][2];
        const bool b3 = v > tv[j][3];
        tv[j][3] = b2 ? tv[j][2] : (b3 ? v : tv[j][3]);
        ti[j][3] = b2 ? ti[j][2] : (b3 ? m : ti[j][3]);
        tv[j][2] = b1 ? tv[j][1] : (b2 ? v : tv[j][2]);
        ti[j][2] = b1 ? ti[j][1] : (b2 ? m : ti[j][2]);
        tv[j][1] = b0 ? tv[j][0] : (b1 ? v : tv[j][1]);
        ti[j][1] = b0 ? ti[j][0] : (b1 ? m : ti[j][1]);
        tv[j][0] = b0 ? v : tv[j][0];
        ti[j][0] = b0 ? m : ti[j][0];
      }
    }
  }

  __syncthreads();
  int* idx_lds = (int*)B_lds;
#pragma unroll
  for (int j = 0; j < 4; ++j)
#pragma unroll
    for (int s = 0; s < 4; ++s)
      idx_lds[(qi * 4 + j) * 128 + mi * 4 + s] = ti[j][s];
  __syncthreads();

  double* pv = (double*)A_lds;
  int* piL = (int*)(A_lds + 4096);
  {
    const int r = t >> 3;
    const int slot = t & 7;
    const float* qrow = qp + (size_t)r * KD;
    double bv[4];
    int bi[4];
#pragma unroll
    for (int e = 0; e < 4; ++e) { bv[e] = -DBL_MAX; bi[e] = 0x7fffffff; }

    for (int c = 0; c < 16; ++c) {
      const int m = idx_lds[r * 128 + slot * 16 + c];
      const float* irow = ip + (size_t)m * KD;
      double s0 = 0.0, s1 = 0.0, s2 = 0.0, s3 = 0.0;
#pragma unroll
      for (int k = 0; k < KD; k += 4) {
        const float4 xv = *(const float4*)(qrow + k);
        const float4 yv = *(const float4*)(irow + k);
        s0 = fma((double)xv.x, (double)yv.x, s0);
        s1 = fma((double)xv.y, (double)yv.y, s1);
        s2 = fma((double)xv.z, (double)yv.z, s2);
        s3 = fma((double)xv.w, (double)yv.w, s3);
      }
      const double v = (s0 + s1) + (s2 + s3);
      const bool b0 = BETTER64(v, m, bv[0], bi[0]);
      const bool b1 = BETTER64(v, m, bv[1], bi[1]);
      const bool b2 = BETTER64(v, m, bv[2], bi[2]);
      const bool b3 = BETTER64(v, m, bv[3], bi[3]);
      bv[3] = b2 ? bv[2] : (b3 ? v : bv[3]);
      bi[3] = b2 ? bi[2] : (b3 ? m : bi[3]);
      bv[2] = b1 ? bv[1] : (b2 ? v : bv[2]);
      bi[2] = b1 ? bi[1] : (b2 ? m : bi[2]);
      bv[1] = b0 ? bv[0] : (b1 ? v : bv[1]);
      bi[1] = b0 ? bi[0] : (b1 ? m : bi[1]);
      bv[0] = b0 ? v : bv[0];
      bi[0] = b0 ? m : bi[0];
    }
#pragma unroll
    for (int e = 0; e < 4; ++e) {
      pv[t * 4 + e] = bv[e];
      piL[t * 4 + e] = bi[e];
    }
  }
  __syncthreads();

  if (t < QT) {
    double fv[4];
    int fi[4];
#pragma unroll
    for (int e = 0; e < 4; ++e) { fv[e] = -DBL_MAX; fi[e] = 0x7fffffff; }
    for (int sl = 0; sl < 8; ++sl) {
#pragma unroll
      for (int e = 0; e < 4; ++e) {
        const double v = pv[(t * 8 + sl) * 4 + e];
        const int m = piL[(t * 8 + sl) * 4 + e];
        const bool b0 = BETTER64(v, m, fv[0], fi[0]);
        const bool b1 = BETTER64(v, m, fv[1], fi[1]);
        const bool b2 = BETTER64(v, m, fv[2], fi[2]);
        const bool b3 = BETTER64(v, m, fv[3], fi[3]);
        fv[3] = b2 ? fv[2] : (b3 ? v : fv[3]);
        fi[3] = b2 ? fi[2] : (b3 ? m : fi[3]);
        fv[2] = b1 ? fv[1] : (b2 ? v : fv[2]);
        fi[2] = b1 ? fi[1] : (b2 ? m : fi[2]);
        fv[1] = b0 ? fv[0] : (b1 ? v : fv[1]);
        fi[1] = b0 ? fi[0] : (b1 ? m : fi[1]);
        fv[0] = b0 ? v : fv[0];
        fi[0] = b0 ? m : fi[0];
      }
    }
    int4 o;
    o.x = fi[0]; o.y = fi[1]; o.z = fi[2]; o.w = fi[3];
    *(int4*)(out + ((size_t)b * NQ + qbase + t) * 4) = o;
  }
}

extern "C" void kernel_launch(void* const* d_in, const int* in_sizes, int n_in,
                              void* d_out, int out_size, void* d_ws, size_t ws_size,
                              hipStream_t stream) {
  const float* qry = (const float*)d_in[0];  // (4, 4096, 128) fp32
  const float* img = (const float*)d_in[1];  // (4, 8192, 128) fp32
  int* out = (int*)d_out;                    // (4, 4096, 4) int32

  const size_t qbBytes = (size_t)NBATCH * NQ * KD * sizeof(ushort_t);  // 4 MB
  const size_t ibBytes = (size_t)NBATCH * NM * KD * sizeof(ushort_t);  // 8 MB

  if (ws_size >= qbBytes + ibBytes) {
    ushort_t* qb = (ushort_t*)d_ws;
    int4* ib = (int4*)((char*)d_ws + qbBytes);
    wr_cvt<<<3072, 256, 0, stream>>>(qry, img, qb, ib);
    wr_mfma8<<<256, 512, 0, stream>>>(qry, img, qb, ib, out);
  } else {
    wr_main<<<NBATCH * (NQ / QT), NTHREADS, 0, stream>>>(qry, img, out);
  }
}